// Round 4
// baseline (395.752 us; speedup 1.0000x reference)
//
#include <hip/hip_runtime.h>
#include <math.h>

#define NJ 140
#define NV 13059
#define NB 512
#define NBONES 28

#define MPAD 13184          // 103 * 128
#define KPAD 576            // 140*4 = 560, padded to 18*32
#define NN   1536           // 512 * 3
#define BM   128
#define BN   96
#define KSTEPS 18
#define GRID 512
#define NTILES ((MPAD/BM)*(NN/BN))   // 103*16 = 1648
#define MAGIC 0x13579BDFu

typedef _Float16 f16x8 __attribute__((ext_vector_type(8)));
typedef _Float16 f16x4 __attribute__((ext_vector_type(4)));
typedef float    f32x4 __attribute__((ext_vector_type(4)));

union SmemU {
    struct {
        float M0[NJ][12];
        float M1[NJ][12];
        int   a0[NJ];
        int   a1[NJ];
    } kin;                    // 14560 B
    float eT[4][32*52];       // 26624 B  (per-wave epilogue transpose)
};

// One kernel, one dispatch. 512 blocks x 256 thr, guaranteed 2 blocks/CU
// resident (VGPR<=256 via launch_bounds, LDS 26.6KB, 512 thr/CU) -> the
// device-scope flag barrier cannot deadlock.
__global__ __launch_bounds__(256, 2) void fused_kernel(
    const float* __restrict__ pose,         // (NB, NJ*3)
    const float* __restrict__ bone_lengths, // (NB, NBONES)
    const float* __restrict__ cbl,          // (NB)
    const float* __restrict__ trans,        // (NB, 3)
    const float* __restrict__ scale,        // (NB)
    const float* __restrict__ v_template,   // (NV, 3)
    const float* __restrict__ t_pose,       // (NJ, 3)
    const int*   __restrict__ parent,       // (NJ)
    const int*   __restrict__ bone_mapper,  // (NJ)
    const float* __restrict__ weights,      // (NV, NJ)
    _Float16* __restrict__ A,               // ws: (MPAD, KPAD)
    _Float16* __restrict__ Bt,              // ws: (NN, KPAD)
    unsigned int* __restrict__ flags,       // ws: (GRID)
    float* __restrict__ vout,               // (NB, NV, 3)
    float* __restrict__ jout)               // (NB, NJ, 3)
{
    __shared__ SmemU sm;
    const int t   = threadIdx.x;
    const int blk = blockIdx.x;

    // ================= Phase 1a: kinematics for batch b = blk ===============
    {
        const int b = blk;
        if (t < NJ) {
            const int j = t;
            float z = pose[b*(NJ*3) + 3*j + 0];
            float y = pose[b*(NJ*3) + 3*j + 1];
            float x = pose[b*(NJ*3) + 3*j + 2];
            float cx = cosf(x), sx = sinf(x);
            float cy = cosf(y), sy = sinf(y);
            float cz = cosf(z), sz = sinf(z);
            float r00 = cz*cy;
            float r01 = cz*sy*sx - sz*cx;
            float r02 = cz*sy*cx + sz*sx;
            float r10 = sz*cy;
            float r11 = sz*sy*sx + cz*cx;
            float r12 = sz*sy*cx - cz*sx;
            float r20 = -sy;
            float r21 = cy*sx;
            float r22 = cy*cx;
            float t0, t1, t2;
            int p = parent[j];
            if (j == 0) {
                t0 = t_pose[0]; t1 = t_pose[1]; t2 = t_pose[2];
            } else {
                float ox = t_pose[3*j+0] - t_pose[3*p+0];
                float oy = t_pose[3*j+1] - t_pose[3*p+1];
                float oz = t_pose[3*j+2] - t_pose[3*p+2];
                float s;
                if (j == 1) {
                    s = cbl[b];
                } else {
                    int blid = bone_mapper[j];
                    if (blid >= 0) {
                        float bv = bone_lengths[b*NBONES + blid];
                        s = 2.0f / (1.0f + expf(-bv*0.2f));   // 2*sigmoid(x/5)
                    } else {
                        s = 1.0f;
                    }
                }
                t0 = ox*s; t1 = oy*s; t2 = oz*s;
            }
            sm.kin.M0[j][0]=r00; sm.kin.M0[j][1]=r01; sm.kin.M0[j][2]=r02;  sm.kin.M0[j][3]=t0;
            sm.kin.M0[j][4]=r10; sm.kin.M0[j][5]=r11; sm.kin.M0[j][6]=r12;  sm.kin.M0[j][7]=t1;
            sm.kin.M0[j][8]=r20; sm.kin.M0[j][9]=r21; sm.kin.M0[j][10]=r22; sm.kin.M0[j][11]=t2;
            sm.kin.a0[j] = (j == 0) ? -1 : p;
        }
        __syncthreads();

        float* src = &sm.kin.M0[0][0]; float* dst = &sm.kin.M1[0][0];
        int* as = sm.kin.a0; int* ad = sm.kin.a1;
        for (int r = 0; r < 8; ++r) {
            if (t < NJ) {
                int a = as[t];
                const float* Mi = src + t*12;
                float* Do = dst + t*12;
                if (a >= 0) {
                    const float* Mp = src + a*12;
                    #pragma unroll
                    for (int m = 0; m < 3; ++m) {
                        float p0 = Mp[m*4+0], p1 = Mp[m*4+1], p2 = Mp[m*4+2], p3 = Mp[m*4+3];
                        Do[m*4+0] = p0*Mi[0] + p1*Mi[4] + p2*Mi[8];
                        Do[m*4+1] = p0*Mi[1] + p1*Mi[5] + p2*Mi[9];
                        Do[m*4+2] = p0*Mi[2] + p1*Mi[6] + p2*Mi[10];
                        Do[m*4+3] = p0*Mi[3] + p1*Mi[7] + p2*Mi[11] + p3;
                    }
                    ad[t] = as[a];
                } else {
                    #pragma unroll
                    for (int e = 0; e < 12; ++e) Do[e] = Mi[e];
                    ad[t] = -1;
                }
            }
            __syncthreads();
            float* tf = src; src = dst; dst = tf;
            int* ti = as; as = ad; ad = ti;
        }

        if (t < NJ) {
            const int j = t;
            const float* G = src + j*12;
            float sb = scale[b];
            float tr0 = trans[b*3+0], tr1 = trans[b*3+1], tr2 = trans[b*3+2];
            float* jo = jout + ((size_t)b*NJ + j)*3;
            jo[0] = G[3]*sb  + tr0;
            jo[1] = G[7]*sb  + tr1;
            jo[2] = G[11]*sb + tr2;
            float jx = t_pose[3*j+0], jy = t_pose[3*j+1], jz = t_pose[3*j+2];
            #pragma unroll
            for (int c = 0; c < 3; ++c) {
                float g0 = G[c*4+0], g1 = G[c*4+1], g2 = G[c*4+2];
                float g3 = G[c*4+3] - (g0*jx + g1*jy + g2*jz);
                f16x4 o;
                o[0] = (_Float16)g0; o[1] = (_Float16)g1;
                o[2] = (_Float16)g2; o[3] = (_Float16)g3;
                *(f16x4*)(Bt + (size_t)(b*3 + c)*KPAD + j*4) = o;
            }
        } else if (t < NJ + 48) {
            int idx = t - NJ;
            int c  = idx >> 4;
            int kk = idx & 15;
            Bt[(size_t)(b*3 + c)*KPAD + 560 + kk] = (_Float16)0.f;
        }
    }

    // ================= Phase 1b: build A (grid-stride) ======================
    // A[v][k] = w[v, k>>2] * {x,y,z,1}[k&3], f16, zero-padded.
    for (int tg = blk*256 + t; tg < MPAD*(KPAD/8); tg += GRID*256) {
        int v   = tg / 72;               // 72 octets per row
        int oct = tg - v*72;
        int k0  = oct*8;
        f16x8 out;
        #pragma unroll
        for (int i = 0; i < 8; ++i) out[i] = (_Float16)0.f;
        if (v < NV) {
            float x = v_template[v*3+0];
            float y = v_template[v*3+1];
            float z = v_template[v*3+2];
            int j0 = oct*2;
            float w0 = (j0     < NJ) ? weights[(size_t)v*NJ + j0    ] : 0.f;
            float w1 = (j0 + 1 < NJ) ? weights[(size_t)v*NJ + j0 + 1] : 0.f;
            out[0] = (_Float16)(w0*x); out[1] = (_Float16)(w0*y);
            out[2] = (_Float16)(w0*z); out[3] = (_Float16)w0;
            out[4] = (_Float16)(w1*x); out[5] = (_Float16)(w1*y);
            out[6] = (_Float16)(w1*z); out[7] = (_Float16)w1;
        }
        *(f16x8*)(A + (size_t)v*KPAD + k0) = out;
    }

    // ================= Device-scope barrier (init-independent) ==============
    __threadfence();
    __syncthreads();
    if (t == 0)
        __hip_atomic_store(&flags[blk], MAGIC, __ATOMIC_RELEASE,
                           __HIP_MEMORY_SCOPE_AGENT);
    for (;;) {
        unsigned ok =
            (__hip_atomic_load(&flags[t],       __ATOMIC_ACQUIRE, __HIP_MEMORY_SCOPE_AGENT) == MAGIC) &
            (__hip_atomic_load(&flags[t + 256], __ATOMIC_ACQUIRE, __HIP_MEMORY_SCOPE_AGENT) == MAGIC);
        if (__syncthreads_and((int)ok)) break;
        __builtin_amdgcn_s_sleep(4);
    }
    __threadfence();

    // ================= Phase 2: GEMM tiles (LDS-free K-loop) ================
    const int lane = t & 63;
    const int wid  = t >> 6;
    const int wm   = wid & 1;         // 0..1 (64 rows)
    const int wn   = wid >> 1;        // 0..1 (48 cols)
    const int ln   = lane & 15;
    const int kq   = lane >> 4;

    for (int tile = blk; tile < NTILES; tile += GRID) {
        const int m0 = (tile >> 4) * BM;    // 103 m-blocks
        const int n0 = (tile & 15) * BN;    // 16  n-blocks

        const _Float16* Ap = A  + (size_t)(m0 + wm*64 + ln)*KPAD + kq*8;
        const _Float16* Bp = Bt + (size_t)(n0 + wn*48 + ln)*KPAD + kq*8;

        f32x4 acc[4][3];
        #pragma unroll
        for (int mi = 0; mi < 4; ++mi)
            #pragma unroll
            for (int ni = 0; ni < 3; ++ni)
                acc[mi][ni] = (f32x4){0.f, 0.f, 0.f, 0.f};

        #pragma unroll 3
        for (int ks = 0; ks < KSTEPS; ++ks) {
            f16x8 af0 = *(const f16x8*)(Ap +            ks*32);
            f16x8 af1 = *(const f16x8*)(Ap + 16*KPAD + ks*32);
            f16x8 af2 = *(const f16x8*)(Ap + 32*KPAD + ks*32);
            f16x8 af3 = *(const f16x8*)(Ap + 48*KPAD + ks*32);
            f16x8 bf0 = *(const f16x8*)(Bp +            ks*32);
            f16x8 bf1 = *(const f16x8*)(Bp + 16*KPAD + ks*32);
            f16x8 bf2 = *(const f16x8*)(Bp + 32*KPAD + ks*32);

            acc[0][0] = __builtin_amdgcn_mfma_f32_16x16x32_f16(af0, bf0, acc[0][0], 0, 0, 0);
            acc[0][1] = __builtin_amdgcn_mfma_f32_16x16x32_f16(af0, bf1, acc[0][1], 0, 0, 0);
            acc[0][2] = __builtin_amdgcn_mfma_f32_16x16x32_f16(af0, bf2, acc[0][2], 0, 0, 0);
            acc[1][0] = __builtin_amdgcn_mfma_f32_16x16x32_f16(af1, bf0, acc[1][0], 0, 0, 0);
            acc[1][1] = __builtin_amdgcn_mfma_f32_16x16x32_f16(af1, bf1, acc[1][1], 0, 0, 0);
            acc[1][2] = __builtin_amdgcn_mfma_f32_16x16x32_f16(af1, bf2, acc[1][2], 0, 0, 0);
            acc[2][0] = __builtin_amdgcn_mfma_f32_16x16x32_f16(af2, bf0, acc[2][0], 0, 0, 0);
            acc[2][1] = __builtin_amdgcn_mfma_f32_16x16x32_f16(af2, bf1, acc[2][1], 0, 0, 0);
            acc[2][2] = __builtin_amdgcn_mfma_f32_16x16x32_f16(af2, bf2, acc[2][2], 0, 0, 0);
            acc[3][0] = __builtin_amdgcn_mfma_f32_16x16x32_f16(af3, bf0, acc[3][0], 0, 0, 0);
            acc[3][1] = __builtin_amdgcn_mfma_f32_16x16x32_f16(af3, bf1, acc[3][1], 0, 0, 0);
            acc[3][2] = __builtin_amdgcn_mfma_f32_16x16x32_f16(af3, bf2, acc[3][2], 0, 0, 0);
        }

        // ---- epilogue: per-wave LDS transpose (stride 52: 2-way = free) ----
        float* eT = sm.eT[wid];
        const int bw = (n0 + wn*48) / 3;    // wave's first batch

        #pragma unroll
        for (int phase = 0; phase < 2; ++phase) {
            #pragma unroll
            for (int mm = 0; mm < 2; ++mm) {
                int mi = phase*2 + mm;
                #pragma unroll
                for (int ni = 0; ni < 3; ++ni) {
                    #pragma unroll
                    for (int r = 0; r < 4; ++r) {
                        int m_loc = mm*16 + (lane>>4)*4 + r;
                        int n_loc = ni*16 + ln;
                        eT[m_loc*52 + n_loc] = acc[mi][ni][r];
                    }
                }
            }
            // same-wave RAW through LDS: lgkmcnt handled by compiler
            #pragma unroll
            for (int it = 0; it < 24; ++it) {
                int flat  = it*64 + lane;       // b_loc*96 + v_loc*3 + c
                int b_loc = flat / 96;
                int f96   = flat - b_loc*96;
                int v_loc = f96 / 3;
                int c     = f96 - v_loc*3;
                int bg = bw + b_loc;
                int vg = m0 + wm*64 + phase*32 + v_loc;
                if (vg < NV) {
                    float val = eT[v_loc*52 + b_loc*3 + c];
                    vout[((size_t)bg*NV + vg)*3 + c] = val * scale[bg] + trans[bg*3 + c];
                }
            }
        }
    }
}

extern "C" void kernel_launch(void* const* d_in, const int* in_sizes, int n_in,
                              void* d_out, int out_size, void* d_ws, size_t ws_size,
                              hipStream_t stream) {
    const float* pose         = (const float*)d_in[0];
    const float* bone_lengths = (const float*)d_in[1];
    const float* cbl          = (const float*)d_in[2];
    const float* trans        = (const float*)d_in[3];
    const float* scale        = (const float*)d_in[4];
    const float* v_template   = (const float*)d_in[5];
    const float* t_pose       = (const float*)d_in[6];
    const float* weights      = (const float*)d_in[7];
    const int*   parent       = (const int*)d_in[8];
    const int*   bone_mapper  = (const int*)d_in[9];

    float* vout = (float*)d_out;                          // (NB,NV,3)
    float* jout = vout + (size_t)NB*NV*3;                 // (NB,NJ,3)

    unsigned int* flags = (unsigned int*)d_ws;            // 512 * 4 B
    _Float16* A  = (_Float16*)((char*)d_ws + 2048);       // MPAD*KPAD*2 = 15.19 MB
    _Float16* Bt = A + (size_t)MPAD*KPAD;                 // NN*KPAD*2  =  1.77 MB

    fused_kernel<<<GRID, 256, 0, stream>>>(
        pose, bone_lengths, cbl, trans, scale, v_template, t_pose,
        parent, bone_mapper, weights, A, Bt, flags, vout, jout);
}

// Round 5
// 185.945 us; speedup vs baseline: 2.1283x; 2.1283x over previous
//
#include <hip/hip_runtime.h>
#include <math.h>

#define NJ 140
#define NV 13059
#define NB 512
#define NBONES 28

#define MPAD 13312          // 104*128, zero-padded rows >= NV
#define NPANELS 832         // MPAD/16
#define KPAD 576            // 140*4=560 padded to 18*32
#define NN 1536             // 512*3
#define BNB 128             // n-cols per block
#define LDB 584             // LDS B row stride in f16 (584f16=292dw, 292%32=4 -> uniform banks)
#define MTILES 104          // MPAD/128
#define MC 21               // m-chunks; block i handles tiles mc+21*i
#define GRIDX (12*MC)       // 252 blocks

#define PREP_TG (NPANELS*72*16)   // 958464 A-prep threads
#define PREPB (PREP_TG/256)       // 3744

typedef _Float16 f16x8 __attribute__((ext_vector_type(8)));
typedef _Float16 f16x4 __attribute__((ext_vector_type(4)));
typedef float    f32x4 __attribute__((ext_vector_type(4)));

// ---------------- Kernel 1: fused A-prep + kinematics ----------------------
// blocks [0,512): kinematics for batch b (pointer jumping) -> Bt (f16) + jout
// blocks [512,512+PREPB): A panel layout: element (v,k) at
//   (( (v/16)*72 + k/8 )*16 + v%16)*8 + k%8,  A[v][k] = w[v,k>>2]*{x,y,z,1}[k&3]
__global__ __launch_bounds__(256) void prep_kin_kernel(
    const float* __restrict__ pose,         // (NB, NJ*3)
    const float* __restrict__ bone_lengths, // (NB, NBONES)
    const float* __restrict__ cbl,          // (NB)
    const float* __restrict__ trans,        // (NB, 3)
    const float* __restrict__ scale,        // (NB)
    const float* __restrict__ v_template,   // (NV, 3)
    const float* __restrict__ t_pose,       // (NJ, 3)
    const int*   __restrict__ parent,       // (NJ)
    const int*   __restrict__ bone_mapper,  // (NJ)
    const float* __restrict__ weights,      // (NV, NJ)
    _Float16* __restrict__ A,               // ws: panel layout, NPANELS*72*128
    _Float16* __restrict__ Bt,              // ws: (NN, KPAD)
    float* __restrict__ jout)               // (NB, NJ, 3)
{
    const int t = threadIdx.x;

    if (blockIdx.x >= 512) {
        // ---- A prep: one f16x8 per thread, fully coalesced write ----
        int tg   = (blockIdx.x - 512) * 256 + t;   // [0, 958464)
        int ln   = tg & 15;
        int rest = tg >> 4;
        int kb   = rest % 72;
        int p    = rest / 72;
        int v    = p * 16 + ln;
        f16x8 out;
        #pragma unroll
        for (int i = 0; i < 8; ++i) out[i] = (_Float16)0.f;
        if (v < NV) {
            float x = v_template[v*3+0];
            float y = v_template[v*3+1];
            float z = v_template[v*3+2];
            int j0 = kb * 2;
            if (j0 < NJ) {
                float w0 = weights[(size_t)v*NJ + j0];
                out[0] = (_Float16)(w0*x); out[1] = (_Float16)(w0*y);
                out[2] = (_Float16)(w0*z); out[3] = (_Float16)w0;
            }
            if (j0 + 1 < NJ) {
                float w1 = weights[(size_t)v*NJ + j0 + 1];
                out[4] = (_Float16)(w1*x); out[5] = (_Float16)(w1*y);
                out[6] = (_Float16)(w1*z); out[7] = (_Float16)w1;
            }
        }
        *(f16x8*)(A + (size_t)tg * 8) = out;
        return;
    }

    // ---- kinematics for batch b = blockIdx.x ----
    __shared__ float M0[NJ][12];
    __shared__ float M1[NJ][12];
    __shared__ int   a0[NJ];
    __shared__ int   a1[NJ];

    const int b = blockIdx.x;

    if (t < NJ) {
        const int j = t;
        float z = pose[b*(NJ*3) + 3*j + 0];
        float y = pose[b*(NJ*3) + 3*j + 1];
        float x = pose[b*(NJ*3) + 3*j + 2];
        float cx = cosf(x), sx = sinf(x);
        float cy = cosf(y), sy = sinf(y);
        float cz = cosf(z), sz = sinf(z);
        float r00 = cz*cy;
        float r01 = cz*sy*sx - sz*cx;
        float r02 = cz*sy*cx + sz*sx;
        float r10 = sz*cy;
        float r11 = sz*sy*sx + cz*cx;
        float r12 = sz*sy*cx - cz*sx;
        float r20 = -sy;
        float r21 = cy*sx;
        float r22 = cy*cx;
        float t0, t1, t2;
        int p = parent[j];
        if (j == 0) {
            t0 = t_pose[0]; t1 = t_pose[1]; t2 = t_pose[2];
        } else {
            float ox = t_pose[3*j+0] - t_pose[3*p+0];
            float oy = t_pose[3*j+1] - t_pose[3*p+1];
            float oz = t_pose[3*j+2] - t_pose[3*p+2];
            float s;
            if (j == 1) {
                s = cbl[b];
            } else {
                int blid = bone_mapper[j];
                if (blid >= 0) {
                    float bv = bone_lengths[b*NBONES + blid];
                    s = 2.0f / (1.0f + expf(-bv*0.2f));   // 2*sigmoid(x/5)
                } else {
                    s = 1.0f;
                }
            }
            t0 = ox*s; t1 = oy*s; t2 = oz*s;
        }
        M0[j][0]=r00; M0[j][1]=r01; M0[j][2]=r02;  M0[j][3]=t0;
        M0[j][4]=r10; M0[j][5]=r11; M0[j][6]=r12;  M0[j][7]=t1;
        M0[j][8]=r20; M0[j][9]=r21; M0[j][10]=r22; M0[j][11]=t2;
        a0[j] = (j == 0) ? -1 : p;
    }
    __syncthreads();

    float* src = &M0[0][0]; float* dst = &M1[0][0];
    int* as = a0; int* ad = a1;
    for (int r = 0; r < 8; ++r) {
        if (t < NJ) {
            int a = as[t];
            const float* Mi = src + t*12;
            float* Do = dst + t*12;
            if (a >= 0) {
                const float* Mp = src + a*12;
                #pragma unroll
                for (int m = 0; m < 3; ++m) {
                    float p0 = Mp[m*4+0], p1 = Mp[m*4+1], p2 = Mp[m*4+2], p3 = Mp[m*4+3];
                    Do[m*4+0] = p0*Mi[0] + p1*Mi[4] + p2*Mi[8];
                    Do[m*4+1] = p0*Mi[1] + p1*Mi[5] + p2*Mi[9];
                    Do[m*4+2] = p0*Mi[2] + p1*Mi[6] + p2*Mi[10];
                    Do[m*4+3] = p0*Mi[3] + p1*Mi[7] + p2*Mi[11] + p3;
                }
                ad[t] = as[a];
            } else {
                #pragma unroll
                for (int e = 0; e < 12; ++e) Do[e] = Mi[e];
                ad[t] = -1;
            }
        }
        __syncthreads();
        float* tf = src; src = dst; dst = tf;
        int* ti = as; as = ad; ad = ti;
    }

    if (t < NJ) {
        const int j = t;
        const float* G = src + j*12;
        float sb = scale[b];
        float tr0 = trans[b*3+0], tr1 = trans[b*3+1], tr2 = trans[b*3+2];
        float* jo = jout + ((size_t)b*NJ + j)*3;
        jo[0] = G[3]*sb  + tr0;
        jo[1] = G[7]*sb  + tr1;
        jo[2] = G[11]*sb + tr2;
        float jx = t_pose[3*j+0], jy = t_pose[3*j+1], jz = t_pose[3*j+2];
        #pragma unroll
        for (int c = 0; c < 3; ++c) {
            float g0 = G[c*4+0], g1 = G[c*4+1], g2 = G[c*4+2];
            float g3 = G[c*4+3] - (g0*jx + g1*jy + g2*jz);
            f16x4 o;
            o[0] = (_Float16)g0; o[1] = (_Float16)g1;
            o[2] = (_Float16)g2; o[3] = (_Float16)g3;
            *(f16x4*)(Bt + (size_t)(b*3 + c)*KPAD + j*4) = o;
        }
    } else if (t < NJ + 48) {
        int idx = t - NJ;
        int c  = idx >> 4;
        int kk = idx & 15;
        Bt[(size_t)(b*3 + c)*KPAD + 560 + kk] = (_Float16)0.f;
    }
}

// ---------------- Kernel 2: GEMM, B-panel in LDS, A streamed ---------------
// 252 blocks x 512 thr (8 waves), 1 block/CU. Whole B n-slice (128x576 f16,
// 149.5 KB) staged to LDS once (ONE barrier). 5 m-tiles/block, 18 K-steps,
// wave = 64m x 32n: 4 af (1KB contiguous global each) + 2 bf (LDS) + 8 MFMA.
// No barriers in K-loop -> compiler pipelines loads across iterations.
__global__ __launch_bounds__(512) void gemm_kernel(
    const _Float16* __restrict__ A,        // panel layout (see prep)
    const _Float16* __restrict__ Bt,       // (NN, KPAD) row-major
    const float* __restrict__ scale,       // (NB)
    const float* __restrict__ trans,       // (NB, 3) flat
    float* __restrict__ vout)              // (NB, NV, 3)
{
    __shared__ _Float16 sB[BNB * LDB];     // 149504 B

    const int t    = threadIdx.x;
    const int lane = t & 63;
    const int wid  = t >> 6;
    const int wm   = wid & 1;        // 0..1 : 64-row m-group
    const int wn   = wid >> 1;       // 0..3 : 32-col n-group
    const int ln   = lane & 15;
    const int kq   = lane >> 4;      // 0..3

    const int nb = blockIdx.x % 12;
    const int mc = blockIdx.x / 12;  // [0,21)
    const int n0 = nb * BNB;

    // ---- stage B slice (coalesced 16B chunks), one barrier ----
    for (int c = t; c < BNB*72; c += 512) {
        int row = c / 72;
        int oct = c - row*72;
        f16x8 v = *(const f16x8*)(Bt + (size_t)(n0 + row)*KPAD + oct*8);
        *(f16x8*)(sB + row*LDB + oct*8) = v;
    }
    __syncthreads();

    // ---- per-lane epilogue constants ----
    long long obase[2]; float es[2], etr[2];
    #pragma unroll
    for (int ni = 0; ni < 2; ++ni) {
        int n  = n0 + wn*32 + ni*16 + ln;
        int bq = n / 3;
        int cr = n - bq*3;
        obase[ni] = (long long)bq*(NV*3) + cr;
        es[ni]  = scale[bq];
        etr[ni] = trans[n];
    }

    const _Float16* bp = sB + (wn*32 + ln)*LDB + kq*8;

    for (int i = 0; i < 5; ++i) {
        const int id = mc + MC*i;
        if (id >= MTILES) break;

        // A panel base: p = id*8 + wm*4 + mi; addr = (p*72 + ks*4+kq)*128 + ln*8
        const _Float16* ap = A + ((size_t)(id*8 + wm*4)*72 + kq)*128 + ln*8;

        f32x4 acc[4][2];
        #pragma unroll
        for (int mi = 0; mi < 4; ++mi)
            #pragma unroll
            for (int ni = 0; ni < 2; ++ni)
                acc[mi][ni] = (f32x4){0.f, 0.f, 0.f, 0.f};

        #pragma unroll 6
        for (int ks = 0; ks < 18; ++ks) {
            f16x8 bf0 = *(const f16x8*)(bp + ks*32);
            f16x8 bf1 = *(const f16x8*)(bp + 16*LDB + ks*32);
            f16x8 af0 = *(const f16x8*)(ap +         ks*512);
            f16x8 af1 = *(const f16x8*)(ap +  9216 + ks*512);
            f16x8 af2 = *(const f16x8*)(ap + 18432 + ks*512);
            f16x8 af3 = *(const f16x8*)(ap + 27648 + ks*512);

            acc[0][0] = __builtin_amdgcn_mfma_f32_16x16x32_f16(af0, bf0, acc[0][0], 0, 0, 0);
            acc[0][1] = __builtin_amdgcn_mfma_f32_16x16x32_f16(af0, bf1, acc[0][1], 0, 0, 0);
            acc[1][0] = __builtin_amdgcn_mfma_f32_16x16x32_f16(af1, bf0, acc[1][0], 0, 0, 0);
            acc[1][1] = __builtin_amdgcn_mfma_f32_16x16x32_f16(af1, bf1, acc[1][1], 0, 0, 0);
            acc[2][0] = __builtin_amdgcn_mfma_f32_16x16x32_f16(af2, bf0, acc[2][0], 0, 0, 0);
            acc[2][1] = __builtin_amdgcn_mfma_f32_16x16x32_f16(af2, bf1, acc[2][1], 0, 0, 0);
            acc[3][0] = __builtin_amdgcn_mfma_f32_16x16x32_f16(af3, bf0, acc[3][0], 0, 0, 0);
            acc[3][1] = __builtin_amdgcn_mfma_f32_16x16x32_f16(af3, bf1, acc[3][1], 0, 0, 0);
        }

        // ---- epilogue: direct stores (L2 write-combines; tile fully covered)
        const int vbase = id*128 + wm*64 + kq*4;
        #pragma unroll
        for (int mi = 0; mi < 4; ++mi) {
            #pragma unroll
            for (int ni = 0; ni < 2; ++ni) {
                #pragma unroll
                for (int r = 0; r < 4; ++r) {
                    int vg = vbase + mi*16 + r;
                    if (vg < NV)
                        vout[obase[ni] + (long long)vg*3] =
                            acc[mi][ni][r]*es[ni] + etr[ni];
                }
            }
        }
    }
}

extern "C" void kernel_launch(void* const* d_in, const int* in_sizes, int n_in,
                              void* d_out, int out_size, void* d_ws, size_t ws_size,
                              hipStream_t stream) {
    const float* pose         = (const float*)d_in[0];
    const float* bone_lengths = (const float*)d_in[1];
    const float* cbl          = (const float*)d_in[2];
    const float* trans        = (const float*)d_in[3];
    const float* scale        = (const float*)d_in[4];
    const float* v_template   = (const float*)d_in[5];
    const float* t_pose       = (const float*)d_in[6];
    const float* weights      = (const float*)d_in[7];
    const int*   parent       = (const int*)d_in[8];
    const int*   bone_mapper  = (const int*)d_in[9];

    float* vout = (float*)d_out;                          // (NB,NV,3)
    float* jout = vout + (size_t)NB*NV*3;                 // (NB,NJ,3)

    _Float16* A  = (_Float16*)d_ws;                       // 832*72*128 f16 = 15.34 MB
    _Float16* Bt = A + (size_t)NPANELS*72*128;            // NN*KPAD f16 = 1.77 MB

    prep_kin_kernel<<<512 + PREPB, 256, 0, stream>>>(
        pose, bone_lengths, cbl, trans, scale, v_template, t_pose,
        parent, bone_mapper, weights, A, Bt, jout);

    gemm_kernel<<<GRIDX, 512, 0, stream>>>(A, Bt, scale, trans, vout);
}

// Round 6
// 164.678 us; speedup vs baseline: 2.4032x; 1.1291x over previous
//
#include <hip/hip_runtime.h>
#include <math.h>

#define NJ 140
#define NV 13059
#define NB 512
#define NBONES 28

#define MTILES 103                    // 103*128 = 13184 >= NV
#define NBLK 12                       // 1536 / 128
#define KS 18                         // K = 576 = 18*32
#define GRID_GEMM (MTILES*NBLK)       // 1236

#define APREP_SLOTS (MTILES*KS*512)   // 949248 f16x8 slots
#define PREPB (APREP_SLOTS/256)       // 3708

typedef _Float16 f16x8 __attribute__((ext_vector_type(8)));
typedef float    f32x4 __attribute__((ext_vector_type(4)));

// async global->LDS DMA, 16 B per lane; lds base must be wave-uniform
#define GL16(gp, lp) __builtin_amdgcn_global_load_lds( \
    (const __attribute__((address_space(1))) unsigned int*)(gp), \
    (__attribute__((address_space(3))) unsigned int*)(lp), 16, 0, 0)

// ---------------- Kernel 1: fused A-prep + kinematics ----------------------
// Panel layout (both A and B): panel[tile][ks][slot=row*4+cs][8 f16], where
// the slot holds global chunk ci = cs ^ ((row>>1)&3) (bank swizzle), i.e.
// elements [row][k = ks*32 + ci*8 .. +7].
// blocks [0,512): kinematics for batch b -> packed B panels + jout
// blocks [512,512+PREPB): A[v][k] = w[v,k>>2]*{x,y,z,1}[k&3], packed+swizzled
__global__ __launch_bounds__(256) void prep_kin_kernel(
    const float* __restrict__ pose,         // (NB, NJ*3)
    const float* __restrict__ bone_lengths, // (NB, NBONES)
    const float* __restrict__ cbl,          // (NB)
    const float* __restrict__ trans,        // (NB, 3)
    const float* __restrict__ scale,        // (NB)
    const float* __restrict__ v_template,   // (NV, 3)
    const float* __restrict__ t_pose,       // (NJ, 3)
    const int*   __restrict__ parent,       // (NJ)
    const int*   __restrict__ bone_mapper,  // (NJ)
    const float* __restrict__ weights,      // (NV, NJ)
    _Float16* __restrict__ Ap,              // ws: (MTILES, KS, 512, 8)
    _Float16* __restrict__ Bp,              // ws: (NBLK, KS, 512, 8)
    float* __restrict__ jout)               // (NB, NJ, 3)
{
    const int t = threadIdx.x;

    if (blockIdx.x >= 512) {
        // ---- A prep: one packed f16x8 slot per thread ----
        int tg   = (blockIdx.x - 512) * 256 + t;   // [0, 949248)
        int mt   = tg / (KS*512);
        int r    = tg - mt*(KS*512);
        int ks   = r >> 9;
        int slot = r & 511;
        int row  = slot >> 2;
        int cs   = slot & 3;
        int ci   = cs ^ ((row >> 1) & 3);
        int v    = mt*128 + row;
        int j0   = ks*8 + ci*2;
        f16x8 out;
        #pragma unroll
        for (int i = 0; i < 8; ++i) out[i] = (_Float16)0.f;
        if (v < NV) {
            float x = v_template[v*3+0];
            float y = v_template[v*3+1];
            float z = v_template[v*3+2];
            if (j0 < NJ) {
                float w0 = weights[(size_t)v*NJ + j0];
                out[0] = (_Float16)(w0*x); out[1] = (_Float16)(w0*y);
                out[2] = (_Float16)(w0*z); out[3] = (_Float16)w0;
            }
            if (j0 + 1 < NJ) {
                float w1 = weights[(size_t)v*NJ + j0 + 1];
                out[4] = (_Float16)(w1*x); out[5] = (_Float16)(w1*y);
                out[6] = (_Float16)(w1*z); out[7] = (_Float16)w1;
            }
        }
        *(f16x8*)(Ap + (size_t)tg * 8) = out;
        return;
    }

    // ---- kinematics for batch b = blockIdx.x ----
    __shared__ float M0[NJ][12];
    __shared__ float M1[NJ][12];
    __shared__ int   a0[NJ];
    __shared__ int   a1[NJ];

    const int b = blockIdx.x;

    if (t < NJ) {
        const int j = t;
        float z = pose[b*(NJ*3) + 3*j + 0];
        float y = pose[b*(NJ*3) + 3*j + 1];
        float x = pose[b*(NJ*3) + 3*j + 2];
        float cx = cosf(x), sx = sinf(x);
        float cy = cosf(y), sy = sinf(y);
        float cz = cosf(z), sz = sinf(z);
        float r00 = cz*cy;
        float r01 = cz*sy*sx - sz*cx;
        float r02 = cz*sy*cx + sz*sx;
        float r10 = sz*cy;
        float r11 = sz*sy*sx + cz*cx;
        float r12 = sz*sy*cx - cz*sx;
        float r20 = -sy;
        float r21 = cy*sx;
        float r22 = cy*cx;
        float t0, t1, t2;
        int p = parent[j];
        if (j == 0) {
            t0 = t_pose[0]; t1 = t_pose[1]; t2 = t_pose[2];
        } else {
            float ox = t_pose[3*j+0] - t_pose[3*p+0];
            float oy = t_pose[3*j+1] - t_pose[3*p+1];
            float oz = t_pose[3*j+2] - t_pose[3*p+2];
            float s;
            if (j == 1) {
                s = cbl[b];
            } else {
                int blid = bone_mapper[j];
                if (blid >= 0) {
                    float bv = bone_lengths[b*NBONES + blid];
                    s = 2.0f / (1.0f + expf(-bv*0.2f));   // 2*sigmoid(x/5)
                } else {
                    s = 1.0f;
                }
            }
            t0 = ox*s; t1 = oy*s; t2 = oz*s;
        }
        M0[j][0]=r00; M0[j][1]=r01; M0[j][2]=r02;  M0[j][3]=t0;
        M0[j][4]=r10; M0[j][5]=r11; M0[j][6]=r12;  M0[j][7]=t1;
        M0[j][8]=r20; M0[j][9]=r21; M0[j][10]=r22; M0[j][11]=t2;
        a0[j] = (j == 0) ? -1 : p;
    }
    __syncthreads();

    float* src = &M0[0][0]; float* dst = &M1[0][0];
    int* as = a0; int* ad = a1;
    for (int r = 0; r < 8; ++r) {
        if (t < NJ) {
            int a = as[t];
            const float* Mi = src + t*12;
            float* Do = dst + t*12;
            if (a >= 0) {
                const float* Mp = src + a*12;
                #pragma unroll
                for (int m = 0; m < 3; ++m) {
                    float p0 = Mp[m*4+0], p1 = Mp[m*4+1], p2 = Mp[m*4+2], p3 = Mp[m*4+3];
                    Do[m*4+0] = p0*Mi[0] + p1*Mi[4] + p2*Mi[8];
                    Do[m*4+1] = p0*Mi[1] + p1*Mi[5] + p2*Mi[9];
                    Do[m*4+2] = p0*Mi[2] + p1*Mi[6] + p2*Mi[10];
                    Do[m*4+3] = p0*Mi[3] + p1*Mi[7] + p2*Mi[11] + p3;
                }
                ad[t] = as[a];
            } else {
                #pragma unroll
                for (int e = 0; e < 12; ++e) Do[e] = Mi[e];
                ad[t] = -1;
            }
        }
        __syncthreads();
        float* tf = src; src = dst; dst = tf;
        int* ti = as; as = ad; ad = ti;
    }

    // G_rel (fp32) into the spare LDS buffer, then pack to B panels
    float* grl = dst;   // [NJ][12], dst != src after even # of swaps
    if (t < NJ) {
        const int j = t;
        const float* G = src + j*12;
        float sb = scale[b];
        float tr0 = trans[b*3+0], tr1 = trans[b*3+1], tr2 = trans[b*3+2];
        float* jo = jout + ((size_t)b*NJ + j)*3;
        jo[0] = G[3]*sb  + tr0;
        jo[1] = G[7]*sb  + tr1;
        jo[2] = G[11]*sb + tr2;
        float jx = t_pose[3*j+0], jy = t_pose[3*j+1], jz = t_pose[3*j+2];
        #pragma unroll
        for (int c = 0; c < 3; ++c) {
            float g0 = G[c*4+0], g1 = G[c*4+1], g2 = G[c*4+2];
            float g3 = G[c*4+3] - (g0*jx + g1*jy + g2*jz);
            grl[j*12 + c*4 + 0] = g0;
            grl[j*12 + c*4 + 1] = g1;
            grl[j*12 + c*4 + 2] = g2;
            grl[j*12 + c*4 + 3] = g3;
        }
    }
    __syncthreads();

    // pack: 3 rows x 18 ks x 4 ci = 216 f16x8 slots
    if (t < 216) {
        int c  = t / 72;
        int rr = t - c*72;
        int ks = rr >> 2;
        int ci = rr & 3;
        int nrow = b*3 + c;
        int nb = nrow >> 7;
        int rl = nrow & 127;
        int j0 = ks*8 + ci*2;
        f16x8 o;
        #pragma unroll
        for (int i = 0; i < 8; ++i) o[i] = (_Float16)0.f;
        if (j0 < NJ) {
            o[0] = (_Float16)grl[j0*12 + c*4 + 0];
            o[1] = (_Float16)grl[j0*12 + c*4 + 1];
            o[2] = (_Float16)grl[j0*12 + c*4 + 2];
            o[3] = (_Float16)grl[j0*12 + c*4 + 3];
        }
        if (j0 + 1 < NJ) {
            o[4] = (_Float16)grl[(j0+1)*12 + c*4 + 0];
            o[5] = (_Float16)grl[(j0+1)*12 + c*4 + 1];
            o[6] = (_Float16)grl[(j0+1)*12 + c*4 + 2];
            o[7] = (_Float16)grl[(j0+1)*12 + c*4 + 3];
        }
        int cs = ci ^ ((rl >> 1) & 3);
        *(f16x8*)(Bp + ((size_t)(nb*KS + ks)*512 + rl*4 + cs)*8) = o;
    }
}

// ---------------- Kernel 2: m97-style dbuf MFMA GEMM -----------------------
// 1236 blocks x 256 thr (4 waves 2m x 2n), tile 128x128, BK=32, 18 K-steps.
// Stage = 4 global_load_lds_dwordx4/thread from contiguous packed panels.
// One barrier per K-step; next stage issued after barrier, overlapping MFMA.
__global__ __launch_bounds__(256) void gemm_kernel(
    const _Float16* __restrict__ Ap,       // (MTILES, KS, 512, 8)
    const _Float16* __restrict__ Bp,       // (NBLK, KS, 512, 8)
    const float* __restrict__ scale,       // (NB)
    const float* __restrict__ trans,       // (NB*3) flat
    float* __restrict__ vout)              // (NB, NV, 3)
{
    __shared__ _Float16 sA[2][4096];       // 16 KB
    __shared__ _Float16 sB[2][4096];       // 16 KB

    const int t    = threadIdx.x;
    const int lane = t & 63;
    const int wid  = t >> 6;
    const int ln   = lane & 15;
    const int kq   = lane >> 4;
    const int wm   = wid & 1;
    const int wn   = wid >> 1;

    const int mt = blockIdx.x / NBLK;
    const int nb = blockIdx.x % NBLK;

    const _Float16* Ag = Ap + (size_t)mt*(KS*4096);
    const _Float16* Bg = Bp + (size_t)nb*(KS*4096);

    const int c1 = wid*64 + lane;          // staging chunk ids (16 B each)
    const int c2 = c1 + 256;
    const int lb1 = wid*512;               // wave-uniform LDS f16 offsets
    const int lb2 = 2048 + wid*512;

    // fragment read offsets (bank-swizzled; 2-way conflict = free)
    const int csl = kq ^ ((ln >> 1) & 3);
    const int rA  = wm*64 + ln;
    const int rB  = wn*64 + ln;
    const int afo = rA*32 + csl*8;         // + mi*512
    const int bfo = rB*32 + csl*8;         // + ni*512

    f32x4 acc[4][4];
    #pragma unroll
    for (int mi = 0; mi < 4; ++mi)
        #pragma unroll
        for (int ni = 0; ni < 4; ++ni)
            acc[mi][ni] = (f32x4){0.f, 0.f, 0.f, 0.f};

    // epilogue constants
    long long obase[4]; float es[4], etr[4];
    #pragma unroll
    for (int ni = 0; ni < 4; ++ni) {
        int n  = nb*128 + wn*64 + ni*16 + ln;
        int bq = n / 3;
        int cr = n - bq*3;
        obase[ni] = (long long)bq*(NV*3) + cr;
        es[ni]  = scale[bq];
        etr[ni] = trans[n];
    }

    auto stage = [&](int buf, int ks) {
        const _Float16* a = Ag + ks*4096;
        const _Float16* b = Bg + ks*4096;
        GL16(a + c1*8, &sA[buf][lb1]);
        GL16(a + c2*8, &sA[buf][lb2]);
        GL16(b + c1*8, &sB[buf][lb1]);
        GL16(b + c2*8, &sB[buf][lb2]);
    };
    auto compute = [&](int buf) {
        f16x8 af[4], bf[4];
        #pragma unroll
        for (int mi = 0; mi < 4; ++mi)
            af[mi] = *(const f16x8*)&sA[buf][afo + mi*512];
        #pragma unroll
        for (int ni = 0; ni < 4; ++ni)
            bf[ni] = *(const f16x8*)&sB[buf][bfo + ni*512];
        #pragma unroll
        for (int mi = 0; mi < 4; ++mi)
            #pragma unroll
            for (int ni = 0; ni < 4; ++ni)
                acc[mi][ni] = __builtin_amdgcn_mfma_f32_16x16x32_f16(
                    af[mi], bf[ni], acc[mi][ni], 0, 0, 0);
    };

    stage(0, 0);
    #pragma unroll 1
    for (int ks = 0; ks < KS; ks += 2) {
        __syncthreads();                       // drains vmcnt -> buf0 ready
        if (ks + 1 < KS) stage(1, ks + 1);     // overlaps compute(0)
        compute(0);
        __syncthreads();                       // buf1 ready
        if (ks + 2 < KS) stage(0, ks + 2);     // overlaps compute(1)
        compute(1);
    }

    // ---- epilogue: direct scattered-dword stores ----
    const int vb = mt*128 + wm*64 + kq*4;
    #pragma unroll
    for (int mi = 0; mi < 4; ++mi) {
        #pragma unroll
        for (int ni = 0; ni < 4; ++ni) {
            #pragma unroll
            for (int r = 0; r < 4; ++r) {
                int vg = vb + mi*16 + r;
                if (vg < NV)
                    vout[obase[ni] + (long long)vg*3] =
                        acc[mi][ni][r]*es[ni] + etr[ni];
            }
        }
    }
}

extern "C" void kernel_launch(void* const* d_in, const int* in_sizes, int n_in,
                              void* d_out, int out_size, void* d_ws, size_t ws_size,
                              hipStream_t stream) {
    const float* pose         = (const float*)d_in[0];
    const float* bone_lengths = (const float*)d_in[1];
    const float* cbl          = (const float*)d_in[2];
    const float* trans        = (const float*)d_in[3];
    const float* scale        = (const float*)d_in[4];
    const float* v_template   = (const float*)d_in[5];
    const float* t_pose       = (const float*)d_in[6];
    const float* weights      = (const float*)d_in[7];
    const int*   parent       = (const int*)d_in[8];
    const int*   bone_mapper  = (const int*)d_in[9];

    float* vout = (float*)d_out;                          // (NB,NV,3)
    float* jout = vout + (size_t)NB*NV*3;                 // (NB,NJ,3)

    _Float16* Ap = (_Float16*)d_ws;                       // 949248*16 B = 14.5 MB
    _Float16* Bp = Ap + (size_t)APREP_SLOTS*8;            // 12*18*512*16 B = 1.69 MB

    prep_kin_kernel<<<512 + PREPB, 256, 0, stream>>>(
        pose, bone_lengths, cbl, trans, scale, v_template, t_pose,
        parent, bone_mapper, weights, Ap, Bp, jout);

    gemm_kernel<<<GRID_GEMM, 256, 0, stream>>>(Ap, Bp, scale, trans, vout);
}